// Round 4
// baseline (33.824 us; speedup 1.0000x reference)
//
#include <hip/hip_runtime.h>

// B=8, G=128 gt boxes, A=9 anchors, H=W=64, FEAT_STRIDE=16. K = 36864.
// Output overlaps (B, K, G) fp32 = 151 MB -> pure store-BW bound.
// fillBuffer ceiling ~6.7 TB/s -> ~22.5 us ideal.
constexpr int G_BOX = 128;
constexpr int N_A   = 9;
constexpr int KTOT  = 64 * 64 * N_A;   // 36864
constexpr int KPW   = 16;              // k rows per wave (8 stores x 2 rows)
constexpr int KPB   = 4 * KPW;         // 64 k rows per block (4 waves)

typedef float f32x4 __attribute__((ext_vector_type(4)));

__global__ __launch_bounds__(256) void overlaps_kernel(
    const float* __restrict__ gt_boxes,   // (B, 128, 5)
    const float* __restrict__ im_info,    // (B, 3) -- ref uses row 0 only
    const float* __restrict__ anchors,    // (9, 4)
    float* __restrict__ out)              // (B, K, G)
{
    __shared__ float s_g[G_BOX][6];       // x1, y1, x2+1, y2+1, area, nz
    __shared__ float s_anc[N_A * 4];

    const int t = threadIdx.x;
    const int b = blockIdx.y;

    if (t < G_BOX) {
        const float* gp = gt_boxes + ((size_t)b * G_BOX + t) * 5;
        float x1 = gp[0], y1 = gp[1], x2 = gp[2], y2 = gp[3];
        float gw = x2 - x1 + 1.0f;
        float gh = y2 - y1 + 1.0f;
        s_g[t][0] = x1;
        s_g[t][1] = y1;
        s_g[t][2] = x2 + 1.0f;
        s_g[t][3] = y2 + 1.0f;
        s_g[t][4] = gw * gh;
        s_g[t][5] = ((gw == 1.0f) && (gh == 1.0f)) ? 0.0f : 1.0f;
    }
    if (t < N_A * 4) s_anc[t] = anchors[t];
    __syncthreads();

    const float im_h = im_info[0];
    const float im_w = im_info[1];

    // Wave64-contiguous mapping: a full wave's float4 store covers TWO
    // consecutive k-rows (lanes 0-31 -> row k, lanes 32-63 -> row k+1)
    // = one contiguous 1KB segment, matching fillBuffer's pattern.
    const int wv   = t >> 6;              // wave in block, 0..3
    const int lane = t & 63;
    const int half = lane >> 5;           // row parity within store
    const int lg   = lane & 31;           // g-quad: g = 4*lg .. 4*lg+3
    const int kbase = blockIdx.x * KPB + wv * KPW + half;

    // Hoist this lane's 4 gt boxes into registers (one-time LDS read).
    float gx1[4], gy1[4], gx2p[4], gy2p[4], garea[4], gnz[4];
    #pragma unroll
    for (int j = 0; j < 4; ++j) {
        const float* sg = s_g[4 * lg + j];
        gx1[j] = sg[0]; gy1[j] = sg[1]; gx2p[j] = sg[2];
        gy2p[j] = sg[3]; garea[j] = sg[4]; gnz[j] = sg[5];
    }

    float* outp = out + (((size_t)b * KTOT + kbase) * G_BOX + 4 * lg);

    #pragma unroll
    for (int q = 0; q < KPW / 2; ++q) {
        unsigned k = (unsigned)(kbase + 2 * q);
        unsigned a = k % 9u;
        unsigned s = k / 9u;              // spatial index i*64 + j
        float sxv = (float)((s & 63u) * 16u);
        float syv = (float)((s >> 6) * 16u);
        float x1 = s_anc[a * 4 + 0] + sxv;
        float y1 = s_anc[a * 4 + 1] + syv;
        float x2 = s_anc[a * 4 + 2] + sxv;
        float y2 = s_anc[a * 4 + 3] + syv;
        float aw = x2 - x1 + 1.0f;
        float ah = y2 - y1 + 1.0f;
        float ax2p = x2 + 1.0f;
        float ay2p = y2 + 1.0f;
        float aarea = aw * ah;
        bool a_zero = (aw == 1.0f) && (ah == 1.0f);
        bool inside = (x1 >= 0.0f) && (y1 >= 0.0f) && (x2 < im_w) && (y2 < im_h);
        bool sel = a_zero || !inside;     // -> -1 regardless of IoU

        f32x4 v;
        #pragma unroll
        for (int j = 0; j < 4; ++j) {
            float ix1  = fmaxf(x1, gx1[j]);
            float iy1  = fmaxf(y1, gy1[j]);
            float ix2p = fminf(ax2p, gx2p[j]);   // = min(x2,gx2)+1 exactly
            float iy2p = fminf(ay2p, gy2p[j]);
            float iw = fmaxf(ix2p - ix1, 0.0f);
            float ih = fmaxf(iy2p - iy1, 0.0f);
            float inter = iw * ih;
            float ua = aarea + garea[j] - inter; // > 0 for this data
            float r = inter * __builtin_amdgcn_rcpf(ua);
            r *= gnz[j];                          // gt_zero -> 0
            v[j] = sel ? -1.0f : r;
        }
        // Non-temporal: 151MB stream, don't keep dirty lines in L2.
        __builtin_nontemporal_store(v,
            reinterpret_cast<f32x4*>(outp + (size_t)(2 * q) * G_BOX));
    }
}

extern "C" void kernel_launch(void* const* d_in, const int* in_sizes, int n_in,
                              void* d_out, int out_size, void* d_ws, size_t ws_size,
                              hipStream_t stream) {
    // inputs: 0=rpn_cls_score (unused), 1=gt_boxes, 2=im_info,
    //         3=num_boxes (unused by reference output), 4=anchors
    const float* gt_boxes = (const float*)d_in[1];
    const float* im_info  = (const float*)d_in[2];
    const float* anchors  = (const float*)d_in[4];
    float* out = (float*)d_out;

    dim3 grid(KTOT / KPB, 8);   // (576, 8)
    dim3 block(256);
    overlaps_kernel<<<grid, block, 0, stream>>>(gt_boxes, im_info, anchors, out);
}

// Round 5
// 30.229 us; speedup vs baseline: 1.1189x; 1.1189x over previous
//
#include <hip/hip_runtime.h>

// B=8, G=128 gt boxes, A=9 anchors, H=W=64, FEAT_STRIDE=16. K = 36864.
// Output overlaps (B, K, G) fp32 = 151 MB -> pure store-BW bound.
// fillBuffer ceiling ~6.7 TB/s -> ~22.5 us ideal.
// R4 lesson: nontemporal stores REGRESS (-18%) on this write stream; L2
// write-combining with normal stores is better. Keep wave64-contiguous 1KB
// stores, normal flags; amortize per-block setup with KPB=128.
constexpr int G_BOX = 128;
constexpr int N_A   = 9;
constexpr int KTOT  = 64 * 64 * N_A;   // 36864
constexpr int KPW   = 32;              // k rows per wave (16 stores x 2 rows)
constexpr int KPB   = 4 * KPW;         // 128 k rows per block (4 waves)

typedef float f32x4 __attribute__((ext_vector_type(4)));

__global__ __launch_bounds__(256) void overlaps_kernel(
    const float* __restrict__ gt_boxes,   // (B, 128, 5)
    const float* __restrict__ im_info,    // (B, 3) -- ref uses row 0 only
    const float* __restrict__ anchors,    // (9, 4)
    float* __restrict__ out)              // (B, K, G)
{
    __shared__ float s_g[G_BOX][6];       // x1, y1, x2+1, y2+1, area, nz
    __shared__ float s_anc[N_A * 4];

    const int t = threadIdx.x;
    const int b = blockIdx.y;

    if (t < G_BOX) {
        const float* gp = gt_boxes + ((size_t)b * G_BOX + t) * 5;
        float x1 = gp[0], y1 = gp[1], x2 = gp[2], y2 = gp[3];
        float gw = x2 - x1 + 1.0f;
        float gh = y2 - y1 + 1.0f;
        s_g[t][0] = x1;
        s_g[t][1] = y1;
        s_g[t][2] = x2 + 1.0f;
        s_g[t][3] = y2 + 1.0f;
        s_g[t][4] = gw * gh;
        s_g[t][5] = ((gw == 1.0f) && (gh == 1.0f)) ? 0.0f : 1.0f;
    }
    if (t < N_A * 4) s_anc[t] = anchors[t];
    __syncthreads();

    const float im_h = im_info[0];
    const float im_w = im_info[1];

    // Wave64-contiguous mapping: one wave float4 store covers TWO consecutive
    // k-rows (lanes 0-31 -> row k, lanes 32-63 -> row k+1) = 1KB contiguous.
    const int wv   = t >> 6;              // wave in block, 0..3
    const int lane = t & 63;
    const int half = lane >> 5;           // row parity within store
    const int lg   = lane & 31;           // g-quad: g = 4*lg .. 4*lg+3
    const int kbase = blockIdx.x * KPB + wv * KPW + half;

    // Hoist this lane's 4 gt boxes into registers (one-time LDS read).
    float gx1[4], gy1[4], gx2p[4], gy2p[4], garea[4], gnz[4];
    #pragma unroll
    for (int j = 0; j < 4; ++j) {
        const float* sg = s_g[4 * lg + j];
        gx1[j] = sg[0]; gy1[j] = sg[1]; gx2p[j] = sg[2];
        gy2p[j] = sg[3]; garea[j] = sg[4]; gnz[j] = sg[5];
    }

    float* outp = out + (((size_t)b * KTOT + kbase) * G_BOX + 4 * lg);

    #pragma unroll
    for (int q = 0; q < KPW / 2; ++q) {
        unsigned k = (unsigned)(kbase + 2 * q);
        unsigned a = k % 9u;
        unsigned s = k / 9u;              // spatial index i*64 + j
        float sxv = (float)((s & 63u) * 16u);
        float syv = (float)((s >> 6) * 16u);
        float x1 = s_anc[a * 4 + 0] + sxv;
        float y1 = s_anc[a * 4 + 1] + syv;
        float x2 = s_anc[a * 4 + 2] + sxv;
        float y2 = s_anc[a * 4 + 3] + syv;
        float aw = x2 - x1 + 1.0f;
        float ah = y2 - y1 + 1.0f;
        float ax2p = x2 + 1.0f;
        float ay2p = y2 + 1.0f;
        float aarea = aw * ah;
        bool a_zero = (aw == 1.0f) && (ah == 1.0f);
        bool inside = (x1 >= 0.0f) && (y1 >= 0.0f) && (x2 < im_w) && (y2 < im_h);
        bool sel = a_zero || !inside;     // -> -1 regardless of IoU

        f32x4 v;
        #pragma unroll
        for (int j = 0; j < 4; ++j) {
            float ix1  = fmaxf(x1, gx1[j]);
            float iy1  = fmaxf(y1, gy1[j]);
            float ix2p = fminf(ax2p, gx2p[j]);   // = min(x2,gx2)+1 exactly
            float iy2p = fminf(ay2p, gy2p[j]);
            float iw = fmaxf(ix2p - ix1, 0.0f);
            float ih = fmaxf(iy2p - iy1, 0.0f);
            float inter = iw * ih;
            float ua = aarea + garea[j] - inter; // > 0 for this data
            float r = inter * __builtin_amdgcn_rcpf(ua);
            r *= gnz[j];                          // gt_zero -> 0
            v[j] = sel ? -1.0f : r;
        }
        *reinterpret_cast<f32x4*>(outp + (size_t)(2 * q) * G_BOX) = v;
    }
}

extern "C" void kernel_launch(void* const* d_in, const int* in_sizes, int n_in,
                              void* d_out, int out_size, void* d_ws, size_t ws_size,
                              hipStream_t stream) {
    // inputs: 0=rpn_cls_score (unused), 1=gt_boxes, 2=im_info,
    //         3=num_boxes (unused by reference output), 4=anchors
    const float* gt_boxes = (const float*)d_in[1];
    const float* im_info  = (const float*)d_in[2];
    const float* anchors  = (const float*)d_in[4];
    float* out = (float*)d_out;

    dim3 grid(KTOT / KPB, 8);   // (288, 8)
    dim3 block(256);
    overlaps_kernel<<<grid, block, 0, stream>>>(gt_boxes, im_info, anchors, out);
}

// Round 6
// 30.007 us; speedup vs baseline: 1.1272x; 1.0074x over previous
//
#include <hip/hip_runtime.h>

// B=8, G=128 gt boxes, A=9 anchors, H=W=64, FEAT_STRIDE=16. K = 36864.
// Output overlaps (B, K, G) fp32 = 151 MB -> pure store-BW bound.
// Measured: store width / lane contiguity = null; nt stores = -18%;
// block count monotone: 9216 blk 28.5us > 4608 blk 28.8 > 2304 blk 30.2.
// This round: 18432 blocks (KPB=16), R1's exact store/lane structure.
constexpr int G_BOX = 128;
constexpr int N_A   = 9;
constexpr int KTOT  = 64 * 64 * N_A;   // 36864
constexpr int KPB   = 16;              // k rows per block
constexpr int KPT   = 2;               // k rows per thread (8 kgroups x 2)

__global__ __launch_bounds__(256) void overlaps_kernel(
    const float* __restrict__ gt_boxes,   // (B, 128, 5)
    const float* __restrict__ im_info,    // (B, 3) -- ref uses row 0 only
    const float* __restrict__ anchors,    // (9, 4)
    float* __restrict__ out)              // (B, K, G)
{
    __shared__ float s_gx1[G_BOX], s_gy1[G_BOX], s_gx2p[G_BOX], s_gy2p[G_BOX];
    __shared__ float s_garea[G_BOX], s_gnz[G_BOX];
    __shared__ float s_anc[N_A * 4];

    const int t = threadIdx.x;
    const int b = blockIdx.y;

    if (t < G_BOX) {
        const float* gp = gt_boxes + ((size_t)b * G_BOX + t) * 5;
        float x1 = gp[0], y1 = gp[1], x2 = gp[2], y2 = gp[3];
        float gw = x2 - x1 + 1.0f;
        float gh = y2 - y1 + 1.0f;
        s_gx1[t] = x1;
        s_gy1[t] = y1;
        s_gx2p[t] = x2 + 1.0f;
        s_gy2p[t] = y2 + 1.0f;
        s_garea[t] = gw * gh;
        s_gnz[t] = ((gw == 1.0f) && (gh == 1.0f)) ? 0.0f : 1.0f;
    }
    if (t < N_A * 4) s_anc[t] = anchors[t];
    __syncthreads();

    const float im_h = im_info[0];
    const float im_w = im_info[1];

    const int lane_g = t & 31;       // g = 32c + lane_g (conflict-free LDS)
    const int kgrp   = t >> 5;       // 0..7
    const int k0     = blockIdx.x * KPB + kgrp * KPT;

    // Per-thread anchor precompute (amortized over all 128 g).
    float ax1[KPT], ay1[KPT], ax2p[KPT], ay2p[KPT], aarea[KPT];
    bool  sel[KPT];
    #pragma unroll
    for (int q = 0; q < KPT; ++q) {
        unsigned k = (unsigned)(k0 + q);
        unsigned a = k % 9u;
        unsigned s = k / 9u;         // spatial index = i*64 + j
        float sxv = (float)((s & 63u) * 16u);
        float syv = (float)((s >> 6) * 16u);
        float x1 = s_anc[a * 4 + 0] + sxv;
        float y1 = s_anc[a * 4 + 1] + syv;
        float x2 = s_anc[a * 4 + 2] + sxv;
        float y2 = s_anc[a * 4 + 3] + syv;
        float aw = x2 - x1 + 1.0f;
        float ah = y2 - y1 + 1.0f;
        ax1[q] = x1;
        ay1[q] = y1;
        ax2p[q] = x2 + 1.0f;
        ay2p[q] = y2 + 1.0f;
        aarea[q] = aw * ah;
        bool a_zero = (aw == 1.0f) && (ah == 1.0f);
        bool inside = (x1 >= 0.0f) && (y1 >= 0.0f) && (x2 < im_w) && (y2 < im_h);
        sel[q] = a_zero || !inside;
    }

    float* outb = out + (size_t)b * KTOT * G_BOX;

    #pragma unroll
    for (int c = 0; c < 4; ++c) {
        int g = c * 32 + lane_g;
        float gx1 = s_gx1[g], gy1 = s_gy1[g];
        float gx2p = s_gx2p[g], gy2p = s_gy2p[g];
        float garea = s_garea[g], gnz = s_gnz[g];
        #pragma unroll
        for (int q = 0; q < KPT; ++q) {
            float ix1  = fmaxf(ax1[q], gx1);
            float iy1  = fmaxf(ay1[q], gy1);
            float ix2p = fminf(ax2p[q], gx2p);   // = min(ax2,gx2)+1 exactly
            float iy2p = fminf(ay2p[q], gy2p);
            float iw = fmaxf(ix2p - ix1, 0.0f);
            float ih = fmaxf(iy2p - iy1, 0.0f);
            float inter = iw * ih;
            float ua = aarea[q] + garea - inter;  // > 0 for this data
            float v = inter * __builtin_amdgcn_rcpf(ua);
            v *= gnz;                             // gt_zero -> 0
            v = sel[q] ? -1.0f : v;               // a_zero / !inside -> -1
            outb[(size_t)(k0 + q) * G_BOX + g] = v;
        }
    }
}

extern "C" void kernel_launch(void* const* d_in, const int* in_sizes, int n_in,
                              void* d_out, int out_size, void* d_ws, size_t ws_size,
                              hipStream_t stream) {
    // inputs: 0=rpn_cls_score (unused), 1=gt_boxes, 2=im_info,
    //         3=num_boxes (unused by reference output), 4=anchors
    const float* gt_boxes = (const float*)d_in[1];
    const float* im_info  = (const float*)d_in[2];
    const float* anchors  = (const float*)d_in[4];
    float* out = (float*)d_out;

    dim3 grid(KTOT / KPB, 8);   // (2304, 8) = 18432 blocks
    dim3 block(256);
    overlaps_kernel<<<grid, block, 0, stream>>>(gt_boxes, im_info, anchors, out);
}

// Round 7
// 28.365 us; speedup vs baseline: 1.1925x; 1.0579x over previous
//
#include <hip/hip_runtime.h>

// B=8, G=128 gt boxes, A=9 anchors, H=W=64, FEAT_STRIDE=16. K = 36864.
// Output overlaps (B, K, G) fp32 = 151 MB -> pure store-BW bound.
//
// Experiment matrix (measured, graph-replay dur_us):
//   KPB=32 scalar stores, 9216 blk : 28.5  <- optimum (this file)
//   KPB=64 float4,        4608 blk : 28.8
//   KPB=64 f4+contig+nt,  4608 blk : 33.8  (nontemporal = -18%, avoid)
//   KPB=128 f4+contig,    2304 blk : 30.2
//   KPB=16 scalar,       18432 blk : 30.0
// Store width / lane contiguity: null. Block count: optimum at 9216.
// Model: fill steady-state ~7.2 TB/s + ~6us fixed -> 151MB ideal ~27us;
// 28.5 is within ~5% = practical store-BW roofline for this size.
constexpr int G_BOX = 128;
constexpr int N_A   = 9;
constexpr int KTOT  = 64 * 64 * N_A;   // 36864
constexpr int KPB   = 32;              // k rows per block
constexpr int KPT   = 4;               // k rows per thread

__global__ __launch_bounds__(256) void overlaps_kernel(
    const float* __restrict__ gt_boxes,   // (B, 128, 5)
    const float* __restrict__ im_info,    // (B, 3) -- ref uses row 0 only
    const float* __restrict__ anchors,    // (9, 4)
    float* __restrict__ out)              // (B, K, G)
{
    __shared__ float s_gx1[G_BOX], s_gy1[G_BOX], s_gx2p[G_BOX], s_gy2p[G_BOX];
    __shared__ float s_garea[G_BOX], s_gnz[G_BOX];
    __shared__ float s_anc[N_A * 4];

    const int t = threadIdx.x;
    const int b = blockIdx.y;

    if (t < G_BOX) {
        const float* gp = gt_boxes + ((size_t)b * G_BOX + t) * 5;
        float x1 = gp[0], y1 = gp[1], x2 = gp[2], y2 = gp[3];
        float gw = x2 - x1 + 1.0f;
        float gh = y2 - y1 + 1.0f;
        s_gx1[t] = x1;
        s_gy1[t] = y1;
        s_gx2p[t] = x2 + 1.0f;
        s_gy2p[t] = y2 + 1.0f;
        s_garea[t] = gw * gh;
        s_gnz[t] = ((gw == 1.0f) && (gh == 1.0f)) ? 0.0f : 1.0f;
    }
    if (t < N_A * 4) s_anc[t] = anchors[t];
    __syncthreads();

    const float im_h = im_info[0];
    const float im_w = im_info[1];

    const int lane_g = t & 31;       // g = 32c + lane_g (conflict-free LDS)
    const int kgrp   = t >> 5;       // 0..7
    const int k0     = blockIdx.x * KPB + kgrp * KPT;

    // Per-thread anchor precompute (amortized over all 128 g).
    float ax1[KPT], ay1[KPT], ax2p[KPT], ay2p[KPT], aarea[KPT];
    bool  sel[KPT];                  // (a_zero || !inside) -> -1 final
    #pragma unroll
    for (int q = 0; q < KPT; ++q) {
        unsigned k = (unsigned)(k0 + q);
        unsigned a = k % 9u;
        unsigned s = k / 9u;         // spatial index = i*64 + j
        float sxv = (float)((s & 63u) * 16u);
        float syv = (float)((s >> 6) * 16u);
        float x1 = s_anc[a * 4 + 0] + sxv;
        float y1 = s_anc[a * 4 + 1] + syv;
        float x2 = s_anc[a * 4 + 2] + sxv;
        float y2 = s_anc[a * 4 + 3] + syv;
        float aw = x2 - x1 + 1.0f;
        float ah = y2 - y1 + 1.0f;
        ax1[q] = x1;
        ay1[q] = y1;
        ax2p[q] = x2 + 1.0f;
        ay2p[q] = y2 + 1.0f;
        aarea[q] = aw * ah;
        bool a_zero = (aw == 1.0f) && (ah == 1.0f);
        bool inside = (x1 >= 0.0f) && (y1 >= 0.0f) && (x2 < im_w) && (y2 < im_h);
        sel[q] = a_zero || !inside;
    }

    float* outb = out + (size_t)b * KTOT * G_BOX;

    #pragma unroll
    for (int c = 0; c < 4; ++c) {
        int g = c * 32 + lane_g;
        float gx1 = s_gx1[g], gy1 = s_gy1[g];
        float gx2p = s_gx2p[g], gy2p = s_gy2p[g];
        float garea = s_garea[g], gnz = s_gnz[g];
        #pragma unroll
        for (int q = 0; q < KPT; ++q) {
            float ix1  = fmaxf(ax1[q], gx1);
            float iy1  = fmaxf(ay1[q], gy1);
            float ix2p = fminf(ax2p[q], gx2p);   // = min(ax2,gx2)+1 exactly
            float iy2p = fminf(ay2p[q], gy2p);
            float iw = fmaxf(ix2p - ix1, 0.0f);
            float ih = fmaxf(iy2p - iy1, 0.0f);
            float inter = iw * ih;
            float ua = aarea[q] + garea - inter;  // > 0 for this data
            float v = inter * __builtin_amdgcn_rcpf(ua);
            v *= gnz;                             // gt_zero -> 0
            v = sel[q] ? -1.0f : v;               // a_zero / !inside -> -1
            // 32 lanes of a kgroup write one contiguous 128B chunk per q.
            outb[(size_t)(k0 + q) * G_BOX + g] = v;
        }
    }
}

extern "C" void kernel_launch(void* const* d_in, const int* in_sizes, int n_in,
                              void* d_out, int out_size, void* d_ws, size_t ws_size,
                              hipStream_t stream) {
    // inputs: 0=rpn_cls_score (unused), 1=gt_boxes, 2=im_info,
    //         3=num_boxes (unused by reference output), 4=anchors
    const float* gt_boxes = (const float*)d_in[1];
    const float* im_info  = (const float*)d_in[2];
    const float* anchors  = (const float*)d_in[4];
    float* out = (float*)d_out;

    dim3 grid(KTOT / KPB, 8);   // (1152, 8) = 9216 blocks
    dim3 block(256);
    overlaps_kernel<<<grid, block, 0, stream>>>(gt_boxes, im_info, anchors, out);
}